// Round 1
// baseline (611.303 us; speedup 1.0000x reference)
//
#include <hip/hip_runtime.h>

#define T_STEPS 48
#define BATCH   48
#define DG      256
#define DH      512
#define S_INNER 3

// ws layout (floats):
//   WhT   : DH*DH          (512*512)   transposed W_h
//   WgT   : DG*DH          (256*512)   transposed W_g
//   ZG    : T*B*DH         (2304*512)  z @ W_g^T precomputed
//   outbuf: 2*BATCH        per-batch loss / acc

__device__ __forceinline__ float wave_reduce_sum(float v) {
  #pragma unroll
  for (int off = 32; off > 0; off >>= 1) v += __shfl_xor(v, off, 64);
  return v;
}

__global__ __launch_bounds__(256)
void transpose_k(const float* __restrict__ in, float* __restrict__ out, int R, int C) {
  __shared__ float tile[32][33];
  int c0 = blockIdx.x * 32, r0 = blockIdx.y * 32;
  int tx = threadIdx.x & 31, ty = threadIdx.x >> 5;
  #pragma unroll
  for (int k = 0; k < 32; k += 8)
    tile[ty + k][tx] = in[(size_t)(r0 + ty + k) * C + (c0 + tx)];
  __syncthreads();
  #pragma unroll
  for (int k = 0; k < 32; k += 8)
    out[(size_t)(c0 + ty + k) * R + (r0 + tx)] = tile[tx][ty + k];
}

__global__ __launch_bounds__(DH, 2)
void zg_kernel(const float* __restrict__ z, const float* __restrict__ WgT,
               float* __restrict__ ZG) {
  const int row0 = blockIdx.x * 8;            // 8 rows of the 2304-row Z matrix
  const int tid = threadIdx.x;                // 512 threads; thread owns output dim
  __shared__ __align__(16) float zl[8][DG];
  for (int i = tid; i < 8 * (DG / 4); i += DH) {
    int r = i >> 6, c = i & 63;
    ((float4*)zl[r])[c] = ((const float4*)(z + (size_t)(row0 + r) * DG))[c];
  }
  __syncthreads();
  float acc[8] = {0.f, 0.f, 0.f, 0.f, 0.f, 0.f, 0.f, 0.f};
  for (int j = 0; j < DG; j += 4) {
    float w0 = WgT[(size_t)(j + 0) * DH + tid];
    float w1 = WgT[(size_t)(j + 1) * DH + tid];
    float w2 = WgT[(size_t)(j + 2) * DH + tid];
    float w3 = WgT[(size_t)(j + 3) * DH + tid];
    #pragma unroll
    for (int r = 0; r < 8; ++r) {
      float4 zz = ((const float4*)zl[r])[j >> 2];
      acc[r] = fmaf(w0, zz.x, acc[r]);
      acc[r] = fmaf(w1, zz.y, acc[r]);
      acc[r] = fmaf(w2, zz.z, acc[r]);
      acc[r] = fmaf(w3, zz.w, acc[r]);
    }
  }
  #pragma unroll
  for (int r = 0; r < 8; ++r)
    ZG[(size_t)(row0 + r) * DH + tid] = acc[r];
}

__global__ __launch_bounds__(DH, 2)
void rnn_main(const float* __restrict__ ZG, const float* __restrict__ WhT,
              const float* __restrict__ bh, const float* __restrict__ gamma,
              const float* __restrict__ beta, const float* __restrict__ W_head,
              const float* __restrict__ b_head, const float* __restrict__ clean,
              float* __restrict__ outbuf) {
  const int b = blockIdx.x;
  const int tid = threadIdx.x;   // 512 threads, thread owns dim tid of h
  const int lane = tid & 63;
  const int wave = tid >> 6;

  __shared__ __align__(16) float hist[T_STEPS][DH];  // 96 KB: h history
  __shared__ __align__(16) float hcur[DH];
  __shared__ __align__(16) float2 actpair[DH];       // {j*DH as int bits, h_prev[j]}
  __shared__ float cbuf[T_STEPS];
  __shared__ float red[16];
  __shared__ float red4[32];
  __shared__ int   wcnt[8];
  __shared__ float lampow[T_STEPS];
  __shared__ __align__(16) float pred[DG];

  const float g_i  = gamma[tid];
  const float be_i = beta[tid];
  const float bh_i = bh[tid];

  if (tid == 0) {
    float p = 1.f;
    for (int k = 0; k < T_STEPS; ++k) { lampow[k] = p; p *= 0.95f; }
  }
  if (tid < 8) wcnt[tid] = 0;
  __syncthreads();

  float h_i = 0.f;

  for (int t = 0; t < T_STEPS; ++t) {
    // ---- base = b_h + (z_t @ Wg^T)  [precomputed]  + W_h h_prev (sparse gather)
    float base_i = bh_i + ZG[((size_t)t * BATCH + b) * DH + tid];
    if (t > 0) {
      int cnt = 0;
      #pragma unroll
      for (int w = 0; w < 8; ++w) cnt += wcnt[w];
      float a0 = 0.f, a1 = 0.f, a2 = 0.f, a3 = 0.f;
      int k = 0;
      for (; k + 4 <= cnt; k += 4) {
        float2 p0 = actpair[k + 0];
        float2 p1 = actpair[k + 1];
        float2 p2 = actpair[k + 2];
        float2 p3 = actpair[k + 3];
        a0 = fmaf(WhT[__float_as_int(p0.x) + tid], p0.y, a0);
        a1 = fmaf(WhT[__float_as_int(p1.x) + tid], p1.y, a1);
        a2 = fmaf(WhT[__float_as_int(p2.x) + tid], p2.y, a2);
        a3 = fmaf(WhT[__float_as_int(p3.x) + tid], p3.y, a3);
      }
      for (; k < cnt; ++k) {
        float2 p0 = actpair[k];
        a0 = fmaf(WhT[__float_as_int(p0.x) + tid], p0.y, a0);
      }
      base_i += (a0 + a1) + (a2 + a3);
    }

    // ---- inner settling: h = relu(LN(base + A h)),  A h via rank-t history sum
    float Ah_i = 0.f;
    for (int inner = 0; inner <= S_INNER; ++inner) {
      float x = base_i + Ah_i;
      // LayerNorm block reduction (sum, sumsq)
      float sa = x, sb = x * x;
      #pragma unroll
      for (int off = 32; off > 0; off >>= 1) {
        sa += __shfl_xor(sa, off, 64);
        sb += __shfl_xor(sb, off, 64);
      }
      if (lane == 0) { red[wave] = sa; red[8 + wave] = sb; }
      __syncthreads();
      float s = 0.f, s2 = 0.f;
      #pragma unroll
      for (int w = 0; w < 8; ++w) { s += red[w]; s2 += red[8 + w]; }
      const float inv = 1.f / (float)DH;
      float mu  = s * inv;
      float var = s2 * inv - mu * mu;
      float rstd = rsqrtf(var + 1e-5f);
      h_i = fmaxf(fmaf((x - mu) * rstd, g_i, be_i), 0.f);
      hcur[tid] = h_i;
      __syncthreads();

      if (inner < S_INNER && t > 0) {
        // dots: c_s = eta * lambda^(t-1-s) * (h_s . h), wave-per-s
        for (int s_idx = wave; s_idx < t; s_idx += 8) {
          const float4* hs4 = (const float4*)hist[s_idx];
          const float4* hc4 = (const float4*)hcur;
          float p = 0.f;
          #pragma unroll
          for (int kk = 0; kk < 2; ++kk) {
            float4 a4 = hs4[lane + 64 * kk];
            float4 c4 = hc4[lane + 64 * kk];
            p += a4.x * c4.x + a4.y * c4.y + a4.z * c4.z + a4.w * c4.w;
          }
          p = wave_reduce_sum(p);
          if (lane == 0) cbuf[s_idx] = p * (0.5f * lampow[t - 1 - s_idx]);
        }
        __syncthreads();
        // weighted history sum: Ah[i] = sum_s c_s * h_s[i]
        float A0 = 0.f, A1 = 0.f;
        int s_idx = 0;
        for (; s_idx + 2 <= t; s_idx += 2) {
          A0 = fmaf(hist[s_idx + 0][tid], cbuf[s_idx + 0], A0);
          A1 = fmaf(hist[s_idx + 1][tid], cbuf[s_idx + 1], A1);
        }
        if (s_idx < t) A0 = fmaf(hist[s_idx][tid], cbuf[s_idx], A0);
        Ah_i = A0 + A1;
      }
    }

    // ---- append history + build compacted active-j list for next timestep
    hist[t][tid] = h_i;
    unsigned long long m = __ballot(h_i != 0.f);
    int myoff = __popcll(m & ((1ull << lane) - 1ull));
    if (lane == 0) wcnt[wave] = __popcll(m);
    __syncthreads();
    int wbase = 0;
    #pragma unroll
    for (int w = 0; w < 8; ++w)
      if (w < wave) wbase += wcnt[w];
    if (h_i != 0.f)
      actpair[wbase + myoff] = make_float2(__int_as_float(tid * DH), h_i);
    __syncthreads();
  }

  // ---- epilogue: pred = h @ W_head^T + b_head (wave-per-row), then loss/acc
  for (int r = wave; r < DG; r += 8) {
    const float4* w4  = (const float4*)(W_head + (size_t)r * DH);
    const float4* hc4 = (const float4*)hcur;
    float p = 0.f;
    #pragma unroll
    for (int kk = 0; kk < 2; ++kk) {
      float4 a4 = w4[lane + 64 * kk];
      float4 c4 = hc4[lane + 64 * kk];
      p += a4.x * c4.x + a4.y * c4.y + a4.z * c4.z + a4.w * c4.w;
    }
    p = wave_reduce_sum(p);
    if (lane == 0) pred[r] = p + b_head[r];
  }
  __syncthreads();

  float sq = 0.f, pc = 0.f, pp = 0.f, cc = 0.f;
  if (tid < DG) {
    float pv = pred[tid];
    float cv = clean[(size_t)b * DG + tid];
    float d = pv - cv;
    sq = d * d; pc = pv * cv; pp = pv * pv; cc = cv * cv;
  }
  #pragma unroll
  for (int off = 32; off > 0; off >>= 1) {
    sq += __shfl_xor(sq, off, 64);
    pc += __shfl_xor(pc, off, 64);
    pp += __shfl_xor(pp, off, 64);
    cc += __shfl_xor(cc, off, 64);
  }
  if (lane == 0) {
    red4[wave * 4 + 0] = sq; red4[wave * 4 + 1] = pc;
    red4[wave * 4 + 2] = pp; red4[wave * 4 + 3] = cc;
  }
  __syncthreads();
  if (tid == 0) {
    float Sq = 0.f, Pc = 0.f, Pp = 0.f, Cc = 0.f;
    #pragma unroll
    for (int w = 0; w < 8; ++w) {
      Sq += red4[w * 4 + 0]; Pc += red4[w * 4 + 1];
      Pp += red4[w * 4 + 2]; Cc += red4[w * 4 + 3];
    }
    outbuf[b]         = Sq / (Cc + 1e-6f);
    outbuf[BATCH + b] = Pc / ((sqrtf(Pp) + 1e-6f) * (sqrtf(Cc) + 1e-6f));
  }
}

__global__ __launch_bounds__(64)
void finalize_k(const float* __restrict__ outbuf, float* __restrict__ out) {
  int tid = threadIdx.x;
  float l = (tid < BATCH) ? outbuf[tid] : 0.f;
  float a = (tid < BATCH) ? outbuf[BATCH + tid] : 0.f;
  #pragma unroll
  for (int off = 32; off > 0; off >>= 1) {
    l += __shfl_xor(l, off, 64);
    a += __shfl_xor(a, off, 64);
  }
  if (tid == 0) {
    out[0] = l * (1.f / (float)BATCH);
    out[1] = a * (1.f / (float)BATCH);
  }
}

extern "C" void kernel_launch(void* const* d_in, const int* in_sizes, int n_in,
                              void* d_out, int out_size, void* d_ws, size_t ws_size,
                              hipStream_t stream) {
  (void)in_sizes; (void)n_in; (void)out_size; (void)ws_size;
  const float* z      = (const float*)d_in[0];
  const float* clean  = (const float*)d_in[1];
  const float* W_h    = (const float*)d_in[2];
  const float* W_g    = (const float*)d_in[3];
  const float* b_h    = (const float*)d_in[4];
  const float* gamma  = (const float*)d_in[5];
  const float* beta   = (const float*)d_in[6];
  const float* W_head = (const float*)d_in[7];
  const float* b_head = (const float*)d_in[8];

  float* wsf    = (float*)d_ws;
  float* WhT    = wsf;                                   // 512*512
  float* WgT    = WhT + (size_t)DH * DH;                 // 256*512
  float* ZG     = WgT + (size_t)DG * DH;                 // 2304*512
  float* outbuf = ZG + (size_t)T_STEPS * BATCH * DH;     // 96

  hipLaunchKernelGGL(transpose_k, dim3(DH / 32, DH / 32), dim3(256), 0, stream,
                     W_h, WhT, DH, DH);
  hipLaunchKernelGGL(transpose_k, dim3(DG / 32, DH / 32), dim3(256), 0, stream,
                     W_g, WgT, DH, DG);
  hipLaunchKernelGGL(zg_kernel, dim3((T_STEPS * BATCH) / 8), dim3(DH), 0, stream,
                     z, WgT, ZG);
  hipLaunchKernelGGL(rnn_main, dim3(BATCH), dim3(DH), 0, stream,
                     ZG, WhT, b_h, gamma, beta, W_head, b_head, clean, outbuf);
  hipLaunchKernelGGL(finalize_k, dim3(1), dim3(64), 0, stream,
                     outbuf, (float*)d_out);
}

// Round 2
// 459.740 us; speedup vs baseline: 1.3297x; 1.3297x over previous
//
#include <hip/hip_runtime.h>
#include <hip/hip_fp16.h>

#define T_STEPS 48
#define BATCH   48
#define DG      256
#define DH      512
#define NPAIR   256   // DH/2
#define S_INNER 3

// ws layout (float slots):
//   Whp   : DH*NPAIR u32    (512*256)   packed half2 W_h^T: Whp[j*256+p] = (W_h[2p][j], W_h[2p+1][j])
//   WgT   : DG*DH           (256*512)   transposed W_g
//   ZG    : T*B*DH          (2304*512)  z @ W_g^T precomputed
//   outbuf: 2*BATCH

__device__ __forceinline__ float wave_reduce_sum(float v) {
  #pragma unroll
  for (int off = 32; off > 0; off >>= 1) v += __shfl_xor(v, off, 64);
  return v;
}

__global__ __launch_bounds__(256)
void transpose_k(const float* __restrict__ in, float* __restrict__ out, int R, int C) {
  __shared__ float tile[32][33];
  int c0 = blockIdx.x * 32, r0 = blockIdx.y * 32;
  int tx = threadIdx.x & 31, ty = threadIdx.x >> 5;
  #pragma unroll
  for (int k = 0; k < 32; k += 8)
    tile[ty + k][tx] = in[(size_t)(r0 + ty + k) * C + (c0 + tx)];
  __syncthreads();
  #pragma unroll
  for (int k = 0; k < 32; k += 8)
    out[(size_t)(c0 + ty + k) * R + (r0 + tx)] = tile[tx][ty + k];
}

// Whp[j*NPAIR + p] = half2( W_h[2p][j], W_h[2p+1][j] )
__global__ __launch_bounds__(256)
void pack_wh(const float* __restrict__ W, unsigned* __restrict__ Wp) {
  __shared__ float tile[64][33];
  int j0 = blockIdx.x * 32;   // 16 j-tiles
  int p0 = blockIdx.y * 32;   // 8 pair-tiles (64 rows)
  int tx = threadIdx.x & 31, ty = threadIdx.x >> 5;
  #pragma unroll
  for (int k = 0; k < 64; k += 8)
    tile[ty + k][tx] = W[(size_t)(2 * p0 + ty + k) * DH + (j0 + tx)];
  __syncthreads();
  #pragma unroll
  for (int k = 0; k < 32; k += 8) {
    int jj = ty + k;
    __half2 v = __floats2half2_rn(tile[2 * tx][jj], tile[2 * tx + 1][jj]);
    Wp[(size_t)(j0 + jj) * NPAIR + (p0 + tx)] = *(unsigned*)&v;
  }
}

__global__ __launch_bounds__(DH, 2)
void zg_kernel(const float* __restrict__ z, const float* __restrict__ WgT,
               float* __restrict__ ZG) {
  const int row0 = blockIdx.x * 8;
  const int tid = threadIdx.x;
  __shared__ __align__(16) float zl[8][DG];
  for (int i = tid; i < 8 * (DG / 4); i += DH) {
    int r = i >> 6, c = i & 63;
    ((float4*)zl[r])[c] = ((const float4*)(z + (size_t)(row0 + r) * DG))[c];
  }
  __syncthreads();
  float acc[8] = {0.f, 0.f, 0.f, 0.f, 0.f, 0.f, 0.f, 0.f};
  for (int j = 0; j < DG; j += 4) {
    float w0 = WgT[(size_t)(j + 0) * DH + tid];
    float w1 = WgT[(size_t)(j + 1) * DH + tid];
    float w2 = WgT[(size_t)(j + 2) * DH + tid];
    float w3 = WgT[(size_t)(j + 3) * DH + tid];
    #pragma unroll
    for (int r = 0; r < 8; ++r) {
      float4 zz = ((const float4*)zl[r])[j >> 2];
      acc[r] = fmaf(w0, zz.x, acc[r]);
      acc[r] = fmaf(w1, zz.y, acc[r]);
      acc[r] = fmaf(w2, zz.z, acc[r]);
      acc[r] = fmaf(w3, zz.w, acc[r]);
    }
  }
  #pragma unroll
  for (int r = 0; r < 8; ++r)
    ZG[(size_t)(row0 + r) * DH + tid] = acc[r];
}

__global__ __launch_bounds__(1024, 4)
void rnn_main(const float* __restrict__ ZG, const unsigned* __restrict__ Whp,
              const float* __restrict__ bh, const float* __restrict__ gamma,
              const float* __restrict__ beta, const float* __restrict__ W_head,
              const float* __restrict__ b_head, const float* __restrict__ clean,
              float* __restrict__ outbuf) {
  const int b = blockIdx.x;
  const int tid  = threadIdx.x;        // 1024 threads = 16 waves
  const int lane = tid & 63;
  const int wave = tid >> 6;           // 0..15
  const int dim  = tid & (DH - 1);     // 0..511
  const bool lower = tid < DH;         // wave-uniform (waves 0..7)
  const int p     = tid & (NPAIR - 1); // 0..255
  const int slice = tid >> 8;          // 0..3  K-slice for matvec

  __shared__ __align__(16) float hist[T_STEPS][DH];   // 96 KB f32 history
  __shared__ __align__(16) float hcur[DH];
  __shared__ __align__(16) float2 actpair[DH + 16];   // {j*NPAIR as int bits, h_j}
  __shared__ __align__(16) float pm[4][DH];           // split-K partials
  __shared__ float red[16];
  __shared__ float red4[64];
  __shared__ int   wcnt[8];
  __shared__ float cbuf[T_STEPS];
  __shared__ float lampow[T_STEPS];
  __shared__ __align__(16) float pred[DG];

  float g_i = 0.f, be_i = 0.f, bh_i = 0.f;
  if (lower) { g_i = gamma[dim]; be_i = beta[dim]; bh_i = bh[dim]; }
  if (tid == 0) {
    float pw = 1.f;
    for (int k = 0; k < T_STEPS; ++k) { lampow[k] = pw; pw *= 0.95f; }
  }
  __syncthreads();

  float h_i = 0.f;
  int cntp = 0;   // padded active count (multiple of 16), uniform

  for (int t = 0; t < T_STEPS; ++t) {
    // ---- matvec: base += W_h h_prev, sparse fp16-pair gather, 4-way split-K
    float2 acc = make_float2(0.f, 0.f);
    if (t > 0) {
      const int m4 = cntp >> 2;   // per-slice trip count (multiple of 4)
      for (int m = 0; m < m4; m += 4) {
        float2 q0 = actpair[slice + 4 * (m + 0)];
        float2 q1 = actpair[slice + 4 * (m + 1)];
        float2 q2 = actpair[slice + 4 * (m + 2)];
        float2 q3 = actpair[slice + 4 * (m + 3)];
        unsigned w0 = Whp[__float_as_int(q0.x) + p];
        unsigned w1 = Whp[__float_as_int(q1.x) + p];
        unsigned w2 = Whp[__float_as_int(q2.x) + p];
        unsigned w3 = Whp[__float_as_int(q3.x) + p];
        float2 f0 = __half22float2(*(__half2*)&w0);
        float2 f1 = __half22float2(*(__half2*)&w1);
        float2 f2 = __half22float2(*(__half2*)&w2);
        float2 f3 = __half22float2(*(__half2*)&w3);
        acc.x = fmaf(f0.x, q0.y, acc.x); acc.y = fmaf(f0.y, q0.y, acc.y);
        acc.x = fmaf(f1.x, q1.y, acc.x); acc.y = fmaf(f1.y, q1.y, acc.y);
        acc.x = fmaf(f2.x, q2.y, acc.x); acc.y = fmaf(f2.y, q2.y, acc.y);
        acc.x = fmaf(f3.x, q3.y, acc.x); acc.y = fmaf(f3.y, q3.y, acc.y);
      }
    }
    ((float2*)pm[slice])[p] = acc;
    __syncthreads();                                   // B-mv

    float base_i = 0.f;
    if (lower)
      base_i = bh_i + ZG[((size_t)t * BATCH + b) * DH + dim]
             + ((pm[0][dim] + pm[1][dim]) + (pm[2][dim] + pm[3][dim]));

    // ---- inner settling
    float Ah_i = 0.f;
    for (int inner = 0; inner <= S_INNER; ++inner) {
      float x = 0.f, sa = 0.f, sb = 0.f;
      if (lower) { x = base_i + Ah_i; sa = x; sb = x * x; }
      #pragma unroll
      for (int off = 32; off > 0; off >>= 1) {
        sa += __shfl_xor(sa, off, 64);
        sb += __shfl_xor(sb, off, 64);
      }
      if (lower && lane == 0) { red[wave] = sa; red[8 + wave] = sb; }
      __syncthreads();                                 // B1
      if (lower) {
        float s = 0.f, s2 = 0.f;
        #pragma unroll
        for (int w = 0; w < 8; ++w) { s += red[w]; s2 += red[8 + w]; }
        const float inv = 1.f / (float)DH;
        float mu  = s * inv;
        float var = s2 * inv - mu * mu;
        float rstd = rsqrtf(var + 1e-5f);
        h_i = fmaxf(fmaf((x - mu) * rstd, g_i, be_i), 0.f);
        hcur[dim] = h_i;
        if (inner == S_INNER) hist[t][dim] = h_i;
      }
      __syncthreads();                                 // B2
      if (inner < S_INNER && t > 0) {
        for (int s_idx = wave; s_idx < t; s_idx += 16) {
          const float4* hs4 = (const float4*)hist[s_idx];
          const float4* hc4 = (const float4*)hcur;
          float pdot = 0.f;
          #pragma unroll
          for (int kk = 0; kk < 2; ++kk) {
            float4 a4 = hs4[lane + 64 * kk];
            float4 c4 = hc4[lane + 64 * kk];
            pdot += a4.x * c4.x + a4.y * c4.y + a4.z * c4.z + a4.w * c4.w;
          }
          pdot = wave_reduce_sum(pdot);
          if (lane == 0) cbuf[s_idx] = pdot * (0.5f * lampow[t - 1 - s_idx]);
        }
        __syncthreads();                               // B3
        if (lower) {
          float A0 = 0.f, A1 = 0.f, A2 = 0.f, A3 = 0.f;
          int s = 0;
          for (; s + 4 <= t; s += 4) {
            A0 = fmaf(hist[s + 0][dim], cbuf[s + 0], A0);
            A1 = fmaf(hist[s + 1][dim], cbuf[s + 1], A1);
            A2 = fmaf(hist[s + 2][dim], cbuf[s + 2], A2);
            A3 = fmaf(hist[s + 3][dim], cbuf[s + 3], A3);
          }
          for (; s < t; ++s) A0 = fmaf(hist[s][dim], cbuf[s], A0);
          Ah_i = (A0 + A1) + (A2 + A3);
        }
      }
    }

    // ---- compaction of active columns for next timestep
    unsigned long long mball = 0ull; int myoff = 0;
    if (lower) {
      mball = __ballot(h_i != 0.f);
      myoff = __popcll(mball & ((1ull << lane) - 1ull));
      if (lane == 0) wcnt[wave] = __popcll(mball);
    }
    __syncthreads();                                   // B4
    int cnt = 0, wbase = 0;
    #pragma unroll
    for (int w = 0; w < 8; ++w) {
      int c = wcnt[w];
      if (w < wave) wbase += c;
      cnt += c;
    }
    if (lower && h_i != 0.f)
      actpair[wbase + myoff] = make_float2(__int_as_float(dim << 8), h_i);
    cntp = (cnt + 15) & ~15;
    if (tid < cntp - cnt)
      actpair[cnt + tid] = make_float2(__int_as_float(0), 0.f);
    __syncthreads();                                   // B5
  }

  // ---- epilogue
  for (int r = wave; r < DG; r += 16) {
    const float4* w4  = (const float4*)(W_head + (size_t)r * DH);
    const float4* hc4 = (const float4*)hcur;
    float pdot = 0.f;
    #pragma unroll
    for (int kk = 0; kk < 2; ++kk) {
      float4 a4 = w4[lane + 64 * kk];
      float4 c4 = hc4[lane + 64 * kk];
      pdot += a4.x * c4.x + a4.y * c4.y + a4.z * c4.z + a4.w * c4.w;
    }
    pdot = wave_reduce_sum(pdot);
    if (lane == 0) pred[r] = pdot + b_head[r];
  }
  __syncthreads();

  float sq = 0.f, pc = 0.f, pp = 0.f, cc = 0.f;
  if (tid < DG) {
    float pv = pred[tid];
    float cv = clean[(size_t)b * DG + tid];
    float d = pv - cv;
    sq = d * d; pc = pv * cv; pp = pv * pv; cc = cv * cv;
  }
  #pragma unroll
  for (int off = 32; off > 0; off >>= 1) {
    sq += __shfl_xor(sq, off, 64);
    pc += __shfl_xor(pc, off, 64);
    pp += __shfl_xor(pp, off, 64);
    cc += __shfl_xor(cc, off, 64);
  }
  if (lane == 0) {
    red4[wave * 4 + 0] = sq; red4[wave * 4 + 1] = pc;
    red4[wave * 4 + 2] = pp; red4[wave * 4 + 3] = cc;
  }
  __syncthreads();
  if (tid == 0) {
    float Sq = 0.f, Pc = 0.f, Pp = 0.f, Cc = 0.f;
    #pragma unroll
    for (int w = 0; w < 16; ++w) {
      Sq += red4[w * 4 + 0]; Pc += red4[w * 4 + 1];
      Pp += red4[w * 4 + 2]; Cc += red4[w * 4 + 3];
    }
    outbuf[b]         = Sq / (Cc + 1e-6f);
    outbuf[BATCH + b] = Pc / ((sqrtf(Pp) + 1e-6f) * (sqrtf(Cc) + 1e-6f));
  }
}

__global__ __launch_bounds__(64)
void finalize_k(const float* __restrict__ outbuf, float* __restrict__ out) {
  int tid = threadIdx.x;
  float l = (tid < BATCH) ? outbuf[tid] : 0.f;
  float a = (tid < BATCH) ? outbuf[BATCH + tid] : 0.f;
  #pragma unroll
  for (int off = 32; off > 0; off >>= 1) {
    l += __shfl_xor(l, off, 64);
    a += __shfl_xor(a, off, 64);
  }
  if (tid == 0) {
    out[0] = l * (1.f / (float)BATCH);
    out[1] = a * (1.f / (float)BATCH);
  }
}

extern "C" void kernel_launch(void* const* d_in, const int* in_sizes, int n_in,
                              void* d_out, int out_size, void* d_ws, size_t ws_size,
                              hipStream_t stream) {
  (void)in_sizes; (void)n_in; (void)out_size; (void)ws_size;
  const float* z      = (const float*)d_in[0];
  const float* clean  = (const float*)d_in[1];
  const float* W_h    = (const float*)d_in[2];
  const float* W_g    = (const float*)d_in[3];
  const float* b_h    = (const float*)d_in[4];
  const float* gamma  = (const float*)d_in[5];
  const float* beta   = (const float*)d_in[6];
  const float* W_head = (const float*)d_in[7];
  const float* b_head = (const float*)d_in[8];

  float* wsf     = (float*)d_ws;
  unsigned* Whp  = (unsigned*)wsf;                        // 512*256 u32
  float* WgT     = wsf + (size_t)DH * NPAIR;              // 256*512
  float* ZG      = WgT + (size_t)DG * DH;                 // 2304*512
  float* outbuf  = ZG + (size_t)T_STEPS * BATCH * DH;     // 96

  hipLaunchKernelGGL(pack_wh, dim3(DH / 32, NPAIR / 32), dim3(256), 0, stream,
                     W_h, Whp);
  hipLaunchKernelGGL(transpose_k, dim3(DG / 32, DH / 32), dim3(256), 0, stream,
                     W_g, WgT, DH, DG);
  hipLaunchKernelGGL(zg_kernel, dim3((T_STEPS * BATCH) / 8), dim3(DH), 0, stream,
                     z, WgT, ZG);
  hipLaunchKernelGGL(rnn_main, dim3(BATCH), dim3(1024), 0, stream,
                     ZG, Whp, b_h, gamma, beta, W_head, b_head, clean, outbuf);
  hipLaunchKernelGGL(finalize_k, dim3(1), dim3(64), 0, stream,
                     outbuf, (float*)d_out);
}

// Round 3
// 455.877 us; speedup vs baseline: 1.3409x; 1.0085x over previous
//
#include <hip/hip_runtime.h>

#define T_STEPS 48
#define BATCH   48
#define DG      256
#define DH      512
#define S_INNER 3

typedef _Float16 hf2 __attribute__((ext_vector_type(2)));

__device__ __forceinline__ hf2 bch(unsigned u) { return __builtin_bit_cast(hf2, u); }
__device__ __forceinline__ unsigned pkh(_Float16 a, _Float16 b) {
  hf2 v{a, b}; return __builtin_bit_cast(unsigned, v);
}
__device__ __forceinline__ float fdot2u(unsigned a, unsigned b, float c) {
#if __has_builtin(__builtin_amdgcn_fdot2)
  return __builtin_amdgcn_fdot2(bch(a), bch(b), c, false);
#else
  hf2 x = bch(a), y = bch(b);
  return fmaf((float)x.x, (float)y.x, fmaf((float)x.y, (float)y.y, c));
#endif
}
__device__ __forceinline__ _Float16 lnr(float x, float mu, float rstd, float g, float be) {
  return (_Float16)fmaxf(fmaf((x - mu) * rstd, g, be), 0.f);
}
__device__ __forceinline__ float wave_reduce_sum(float v) {
  #pragma unroll
  for (int off = 32; off > 0; off >>= 1) v += __shfl_xor(v, off, 64);
  return v;
}

// ---------- weight packing: Whq[j*128 + q] = 4 dims {4q..4q+3} of column j, fp16
__global__ __launch_bounds__(256)
void pack_whq(const float* __restrict__ W, uint2* __restrict__ Wq) {
  int idx = blockIdx.x * 256 + threadIdx.x;   // 65536
  int j = idx & (DH - 1), q = idx >> 9;
  float w0 = W[(size_t)(4 * q + 0) * DH + j];
  float w1 = W[(size_t)(4 * q + 1) * DH + j];
  float w2 = W[(size_t)(4 * q + 2) * DH + j];
  float w3 = W[(size_t)(4 * q + 3) * DH + j];
  uint2 o;
  o.x = pkh((_Float16)w0, (_Float16)w1);
  o.y = pkh((_Float16)w2, (_Float16)w3);
  Wq[(size_t)j * 128 + q] = o;
}

__global__ __launch_bounds__(256)
void transpose_k(const float* __restrict__ in, float* __restrict__ out, int R, int C) {
  __shared__ float tile[32][33];
  int c0 = blockIdx.x * 32, r0 = blockIdx.y * 32;
  int tx = threadIdx.x & 31, ty = threadIdx.x >> 5;
  #pragma unroll
  for (int k = 0; k < 32; k += 8)
    tile[ty + k][tx] = in[(size_t)(r0 + ty + k) * C + (c0 + tx)];
  __syncthreads();
  #pragma unroll
  for (int k = 0; k < 32; k += 8)
    out[(size_t)(c0 + ty + k) * R + (r0 + tx)] = tile[tx][ty + k];
}

__global__ __launch_bounds__(DH, 2)
void zg_kernel(const float* __restrict__ z, const float* __restrict__ WgT,
               float* __restrict__ ZG) {
  const int row0 = blockIdx.x * 8;
  const int tid = threadIdx.x;
  __shared__ __align__(16) float zl[8][DG];
  for (int i = tid; i < 8 * (DG / 4); i += DH) {
    int r = i >> 6, c = i & 63;
    ((float4*)zl[r])[c] = ((const float4*)(z + (size_t)(row0 + r) * DG))[c];
  }
  __syncthreads();
  float acc[8] = {0.f, 0.f, 0.f, 0.f, 0.f, 0.f, 0.f, 0.f};
  for (int j = 0; j < DG; j += 4) {
    float w0 = WgT[(size_t)(j + 0) * DH + tid];
    float w1 = WgT[(size_t)(j + 1) * DH + tid];
    float w2 = WgT[(size_t)(j + 2) * DH + tid];
    float w3 = WgT[(size_t)(j + 3) * DH + tid];
    #pragma unroll
    for (int r = 0; r < 8; ++r) {
      float4 zz = ((const float4*)zl[r])[j >> 2];
      acc[r] = fmaf(w0, zz.x, acc[r]);
      acc[r] = fmaf(w1, zz.y, acc[r]);
      acc[r] = fmaf(w2, zz.z, acc[r]);
      acc[r] = fmaf(w3, zz.w, acc[r]);
    }
  }
  #pragma unroll
  for (int r = 0; r < 8; ++r)
    ZG[(size_t)(row0 + r) * DH + tid] = acc[r];
}

__global__ __launch_bounds__(1024, 4)
void rnn_main(const float* __restrict__ ZG, const uint2* __restrict__ Whq,
              const float* __restrict__ bh, const float* __restrict__ gamma,
              const float* __restrict__ beta, const float* __restrict__ W_head,
              const float* __restrict__ b_head, const float* __restrict__ clean,
              float* __restrict__ outbuf) {
  const int b = blockIdx.x;
  const int tid  = threadIdx.x;         // 1024 threads = 16 waves
  const int lane = tid & 63;
  const int wave = tid >> 6;            // 0..15
  const int dim  = tid & (DH - 1);      // owner dim (lower half)
  const bool lower = tid < DH;          // wave-uniform
  const int q     = tid & 127;          // quad index 0..127
  const int slice = tid >> 7;           // 0..7 split-K slice

  __shared__ __align__(16) unsigned histd[T_STEPS * 256];  // 48KB dim-packed fp16 history
  __shared__ __align__(16) unsigned histp[24 * DH];        // 48KB s-pair-packed fp16 history
  __shared__ __align__(16) float    pm[8 * DH];            // 16KB split-K partials
  __shared__ __align__(16) float    xbuf[DH];
  __shared__ __align__(16) uint2    AP[DH];                // {j*128, half2(h,h)}
  __shared__ __align__(16) float    hcur[DH];
  __shared__ __align__(16) float    pred[DG];
  __shared__ float2 red[8];
  __shared__ float  red4[64];
  __shared__ int    wcnt[8];
  __shared__ float  lampow[T_STEPS];
  __shared__ unsigned cbufh2[24];                          // fp16 c coeffs, s-pairs

  float g_i = 0.f, be_i = 0.f, bh_i = 0.f;
  if (lower) { g_i = gamma[dim]; be_i = beta[dim]; bh_i = bh[dim]; }
  // per-lane 8-dim gamma/beta (dims 4*lane..4*lane+3 and 256+4*lane..)
  float4 gA = ((const float4*)gamma)[lane], gB = ((const float4*)gamma)[64 + lane];
  float4 bA = ((const float4*)beta)[lane],  bB = ((const float4*)beta)[64 + lane];
  if (tid == 0) {
    float pw = 0.5f;                       // eta folded in
    for (int k = 0; k < T_STEPS; ++k) { lampow[k] = pw; pw *= 0.95f; }
  }

  int cntp = 0;    // padded active count (multiple of 32), uniform

  for (int t = 0; t < T_STEPS; ++t) {
    if (tid < 24) cbufh2[tid] = 0u;
    float zg = lower ? ZG[((size_t)t * BATCH + b) * DH + dim] : 0.f;

    // ---- matvec: pm[slice][4q..4q+3] += W_h h_prev over this slice's actives
    hf2 a0{}, a1{}, c0{}, c1{};
    const int n = cntp >> 3;               // per-slice entries, multiple of 4
    if (t > 0 && n > 0) {
      int e = slice;
      uint2 p0 = AP[e], p1 = AP[e + 8], p2 = AP[e + 16], p3 = AP[e + 24];
      uint2 w0 = Whq[p0.x + q], w1 = Whq[p1.x + q];
      uint2 w2 = Whq[p2.x + q], w3 = Whq[p3.x + q];
      for (int m = 4; m < n; m += 4) {
        e += 32;
        uint2 q0 = AP[e], q1 = AP[e + 8], q2 = AP[e + 16], q3 = AP[e + 24];
        uint2 v0 = Whq[q0.x + q], v1 = Whq[q1.x + q];
        uint2 v2 = Whq[q2.x + q], v3 = Whq[q3.x + q];
        a0 += bch(w0.x) * bch(p0.y); c0 += bch(w0.y) * bch(p0.y);
        a1 += bch(w1.x) * bch(p1.y); c1 += bch(w1.y) * bch(p1.y);
        a0 += bch(w2.x) * bch(p2.y); c0 += bch(w2.y) * bch(p2.y);
        a1 += bch(w3.x) * bch(p3.y); c1 += bch(w3.y) * bch(p3.y);
        p0 = q0; p1 = q1; p2 = q2; p3 = q3;
        w0 = v0; w1 = v1; w2 = v2; w3 = v3;
      }
      a0 += bch(w0.x) * bch(p0.y); c0 += bch(w0.y) * bch(p0.y);
      a1 += bch(w1.x) * bch(p1.y); c1 += bch(w1.y) * bch(p1.y);
      a0 += bch(w2.x) * bch(p2.y); c0 += bch(w2.y) * bch(p2.y);
      a1 += bch(w3.x) * bch(p3.y); c1 += bch(w3.y) * bch(p3.y);
    }
    {
      float4 s;
      s.x = (float)a0.x + (float)a1.x; s.y = (float)a0.y + (float)a1.y;
      s.z = (float)c0.x + (float)c1.x; s.w = (float)c0.y + (float)c1.y;
      ((float4*)(pm + slice * DH))[q] = s;
    }
    __syncthreads();                                     // B-mv

    float base_i = 0.f;
    if (lower) {
      base_i = bh_i + zg;
      if (t > 0) {
        float ps = 0.f;
        #pragma unroll
        for (int sl = 0; sl < 8; ++sl) ps += pm[sl * DH + dim];
        base_i += ps;
      }
    }

    // ---- inner settling, 1-publish-barrier scheme
    float x = 0.f, mu = 0.f, rstd = 0.f;
    for (int inr = 0; inr <= S_INNER; ++inr) {
      // owner: x = base + Ah (Ah from cbufh written by previous inner's dots)
      float sa = 0.f, sb = 0.f;
      if (lower) {
        float Ah = 0.f;
        if (inr > 0 && t > 0) {
          const int spn = (t + 1) >> 1;
          float A0 = 0.f, A1 = 0.f;
          int sp = 0;
          for (; sp + 2 <= spn; sp += 2) {
            A0 = fdot2u(histp[(sp + 0) * DH + dim], cbufh2[sp + 0], A0);
            A1 = fdot2u(histp[(sp + 1) * DH + dim], cbufh2[sp + 1], A1);
          }
          if (sp < spn) A0 = fdot2u(histp[sp * DH + dim], cbufh2[sp], A0);
          Ah = A0 + A1;
        }
        x = base_i + Ah;
        xbuf[dim] = x;
        sa = x; sb = x * x;
      }
      #pragma unroll
      for (int off = 32; off > 0; off >>= 1) {
        sa += __shfl_xor(sa, off, 64);
        sb += __shfl_xor(sb, off, 64);
      }
      if (lower && lane == 0) red[wave] = make_float2(sa, sb);
      __syncthreads();                                   // B_a
      {
        float s = 0.f, s2 = 0.f;
        #pragma unroll
        for (int w = 0; w < 8; ++w) { float2 r = red[w]; s += r.x; s2 += r.y; }
        const float inv = 1.f / (float)DH;
        mu = s * inv;
        float var = s2 * inv - mu * mu;
        rstd = rsqrtf(var + 1e-5f);
      }

      if (inr < S_INNER) {
        if (t > 0) {
          // every lane reconstructs h for its 8 dims from xbuf
          float4 xa = ((const float4*)xbuf)[lane];
          float4 xb = ((const float4*)xbuf)[64 + lane];
          unsigned hc0 = pkh(lnr(xa.x, mu, rstd, gA.x, bA.x),
                             lnr(xa.y, mu, rstd, gA.y, bA.y));
          unsigned hc1 = pkh(lnr(xa.z, mu, rstd, gA.z, bA.z),
                             lnr(xa.w, mu, rstd, gA.w, bA.w));
          unsigned hc2 = pkh(lnr(xb.x, mu, rstd, gB.x, bB.x),
                             lnr(xb.y, mu, rstd, gB.y, bB.y));
          unsigned hc3 = pkh(lnr(xb.z, mu, rstd, gB.z, bB.z),
                             lnr(xb.w, mu, rstd, gB.w, bB.w));
          for (int r = wave; r < t; r += 16) {
            const uint2* hrow = (const uint2*)(histd + r * 256);
            uint2 h0 = hrow[lane];        // dims 4l..4l+3
            uint2 h1 = hrow[64 + lane];   // dims 256+4l..
            float pd = fdot2u(h0.x, hc0,
                       fdot2u(h0.y, hc1,
                       fdot2u(h1.x, hc2,
                       fdot2u(h1.y, hc3, 0.f))));
            pd = wave_reduce_sum(pd);
            if (lane == 0) {
              _Float16 ch = (_Float16)(pd * lampow[t - 1 - r]);
              ((unsigned short*)cbufh2)[r] = __builtin_bit_cast(unsigned short, ch);
            }
          }
        }
        __syncthreads();                                 // B_b
      } else {
        // final inner: owners materialize h, append history, build active list
        float h = 0.f;
        unsigned long long mball = 0ull; int myoff = 0;
        if (lower) {
          h = fmaxf(fmaf((x - mu) * rstd, g_i, be_i), 0.f);
          unsigned short hb = __builtin_bit_cast(unsigned short, (_Float16)h);
          ((unsigned short*)histd)[t * 512 + dim] = hb;
          if ((t & 1) == 0)
            histp[(t >> 1) * DH + dim] = (unsigned)hb;       // (h, 0)
          else
            ((unsigned short*)&histp[(t >> 1) * DH + dim])[1] = hb;
          if (t == T_STEPS - 1) hcur[dim] = h;
          mball = __ballot(h != 0.f);
          myoff = __popcll(mball & ((1ull << lane) - 1ull));
          if (lane == 0) wcnt[wave] = __popcll(mball);
        }
        __syncthreads();                                 // B4
        int cnt = 0, wbase = 0;
        #pragma unroll
        for (int w = 0; w < 8; ++w) {
          int c = wcnt[w];
          if (w < wave) wbase += c;
          cnt += c;
        }
        if (lower && h != 0.f) {
          _Float16 hh = (_Float16)h;
          uint2 ent; ent.x = (unsigned)(dim << 7); ent.y = pkh(hh, hh);
          AP[wbase + myoff] = ent;
        }
        cntp = (cnt + 31) & ~31;
        if (tid < cntp - cnt) { uint2 zz; zz.x = 0u; zz.y = 0u; AP[cnt + tid] = zz; }
        __syncthreads();                                 // B5
      }
    }
  }

  // ---- epilogue: pred = h @ W_head^T + b_head, then loss/acc
  for (int r = wave; r < DG; r += 16) {
    const float4* w4  = (const float4*)(W_head + (size_t)r * DH);
    const float4* hc4 = (const float4*)hcur;
    float pdot = 0.f;
    #pragma unroll
    for (int kk = 0; kk < 2; ++kk) {
      float4 a4 = w4[lane + 64 * kk];
      float4 c4 = hc4[lane + 64 * kk];
      pdot += a4.x * c4.x + a4.y * c4.y + a4.z * c4.z + a4.w * c4.w;
    }
    pdot = wave_reduce_sum(pdot);
    if (lane == 0) pred[r] = pdot + b_head[r];
  }
  __syncthreads();

  float sq = 0.f, pc = 0.f, pp = 0.f, cc = 0.f;
  if (tid < DG) {
    float pv = pred[tid];
    float cv = clean[(size_t)b * DG + tid];
    float d = pv - cv;
    sq = d * d; pc = pv * cv; pp = pv * pv; cc = cv * cv;
  }
  #pragma unroll
  for (int off = 32; off > 0; off >>= 1) {
    sq += __shfl_xor(sq, off, 64);
    pc += __shfl_xor(pc, off, 64);
    pp += __shfl_xor(pp, off, 64);
    cc += __shfl_xor(cc, off, 64);
  }
  if (lane == 0) {
    red4[wave * 4 + 0] = sq; red4[wave * 4 + 1] = pc;
    red4[wave * 4 + 2] = pp; red4[wave * 4 + 3] = cc;
  }
  __syncthreads();
  if (tid == 0) {
    float Sq = 0.f, Pc = 0.f, Pp = 0.f, Cc = 0.f;
    #pragma unroll
    for (int w = 0; w < 16; ++w) {
      Sq += red4[w * 4 + 0]; Pc += red4[w * 4 + 1];
      Pp += red4[w * 4 + 2]; Cc += red4[w * 4 + 3];
    }
    outbuf[b]         = Sq / (Cc + 1e-6f);
    outbuf[BATCH + b] = Pc / ((sqrtf(Pp) + 1e-6f) * (sqrtf(Cc) + 1e-6f));
  }
}

__global__ __launch_bounds__(64)
void finalize_k(const float* __restrict__ outbuf, float* __restrict__ out) {
  int tid = threadIdx.x;
  float l = (tid < BATCH) ? outbuf[tid] : 0.f;
  float a = (tid < BATCH) ? outbuf[BATCH + tid] : 0.f;
  #pragma unroll
  for (int off = 32; off > 0; off >>= 1) {
    l += __shfl_xor(l, off, 64);
    a += __shfl_xor(a, off, 64);
  }
  if (tid == 0) {
    out[0] = l * (1.f / (float)BATCH);
    out[1] = a * (1.f / (float)BATCH);
  }
}

extern "C" void kernel_launch(void* const* d_in, const int* in_sizes, int n_in,
                              void* d_out, int out_size, void* d_ws, size_t ws_size,
                              hipStream_t stream) {
  (void)in_sizes; (void)n_in; (void)out_size; (void)ws_size;
  const float* z      = (const float*)d_in[0];
  const float* clean  = (const float*)d_in[1];
  const float* W_h    = (const float*)d_in[2];
  const float* W_g    = (const float*)d_in[3];
  const float* b_h    = (const float*)d_in[4];
  const float* gamma  = (const float*)d_in[5];
  const float* beta   = (const float*)d_in[6];
  const float* W_head = (const float*)d_in[7];
  const float* b_head = (const float*)d_in[8];

  float* wsf     = (float*)d_ws;
  uint2* Whq     = (uint2*)wsf;                           // 65536 uint2 = 131072 f32 slots
  float* WgT     = wsf + 131072;                          // 256*512
  float* ZG      = WgT + (size_t)DG * DH;                 // 2304*512
  float* outbuf  = ZG + (size_t)T_STEPS * BATCH * DH;     // 96

  hipLaunchKernelGGL(pack_whq, dim3(256), dim3(256), 0, stream, W_h, Whq);
  hipLaunchKernelGGL(transpose_k, dim3(DG / 32, DH / 32), dim3(256), 0, stream,
                     W_g, WgT, DH, DG);
  hipLaunchKernelGGL(zg_kernel, dim3((T_STEPS * BATCH) / 8), dim3(DH), 0, stream,
                     z, WgT, ZG);
  hipLaunchKernelGGL(rnn_main, dim3(BATCH), dim3(1024), 0, stream,
                     ZG, Whq, b_h, gamma, beta, W_head, b_head, clean, outbuf);
  hipLaunchKernelGGL(finalize_k, dim3(1), dim3(64), 0, stream,
                     outbuf, (float*)d_out);
}